// Round 6
// baseline (2349.454 us; speedup 1.0000x reference)
//
#include <hip/hip_runtime.h>
#include <hip/hip_bf16.h>
#include <stdint.h>

#define T_N 8192
#define K_N 1024
#define D_N 1024
#define LMBDA 5.0f
#define BIGF 3.0e38f

// ---------------- norms: numpy-pairwise-exact sum of squares per row ----------------
__global__ __launch_bounds__(256) void k_norms(const float* __restrict__ F,
                                               const float* __restrict__ C,
                                               float* __restrict__ sf2,
                                               float* __restrict__ sc2) {
#pragma clang fp contract(off)
  int wave = threadIdx.x >> 6;
  int lane = threadIdx.x & 63;
  int row = blockIdx.x * 4 + wave;
  const float* src;
  float* dst;
  if (row < T_N) { src = F + (size_t)row * D_N; dst = sf2 + row; }
  else           { src = C + (size_t)(row - T_N) * D_N; dst = sc2 + (row - T_N); }
  int leaf = lane >> 3, j = lane & 7;
  const float* p = src + leaf * 128 + j;
  float x = p[0];
  float r = x * x;
#pragma unroll
  for (int i = 1; i < 16; ++i) {
    float y = p[8 * i];
    r = r + y * y;
  }
  r = r + __shfl_xor(r, 1, 64);
  r = r + __shfl_xor(r, 2, 64);
  r = r + __shfl_xor(r, 4, 64);
  r = r + __shfl_xor(r, 8, 64);
  r = r + __shfl_xor(r, 16, 64);
  r = r + __shfl_xor(r, 32, 64);
  if (lane == 0) *dst = r;
}

// ---------------- d2 GEMM: OpenBLAS-faithful f32 (numerics frozen — do not reorder) ----------------
__global__ __launch_bounds__(256) void k_gemm(const float* __restrict__ F,
                                              const float* __restrict__ C,
                                              const float* __restrict__ sf2,
                                              const float* __restrict__ sc2,
                                              float* __restrict__ d2) {
  __shared__ float As[32][68];
  __shared__ float Bs[32][68];
  int t0 = (int)(blockIdx.x >> 4) * 64;
  int k0 = (int)(blockIdx.x & 15) * 64;
  int tid = threadIdx.x;
  int tx = tid & 15, ty = tid >> 4;
  float acc[4][4], p0[4][4], p1[4][4];
#pragma unroll
  for (int i = 0; i < 4; ++i)
#pragma unroll
    for (int j = 0; j < 4; ++j) { acc[i][j] = 0.0f; p0[i][j] = 0.0f; p1[i][j] = 0.0f; }
  int r = tid & 63;
  int cbase = (tid >> 6) * 2;
  for (int d0 = 0; d0 < D_N; d0 += 32) {
    __syncthreads();
#pragma unroll
    for (int p = 0; p < 2; ++p) {
      int c4 = cbase + p;
      float4 va = *(const float4*)&F[(size_t)(t0 + r) * D_N + d0 + c4 * 4];
      As[c4 * 4 + 0][r] = va.x; As[c4 * 4 + 1][r] = va.y;
      As[c4 * 4 + 2][r] = va.z; As[c4 * 4 + 3][r] = va.w;
      float4 vb = *(const float4*)&C[(size_t)(k0 + r) * D_N + d0 + c4 * 4];
      Bs[c4 * 4 + 0][r] = vb.x; Bs[c4 * 4 + 1][r] = vb.y;
      Bs[c4 * 4 + 2][r] = vb.z; Bs[c4 * 4 + 3][r] = vb.w;
    }
    __syncthreads();
#pragma unroll
    for (int d = 0; d < 32; ++d) {
      float4 a = *(const float4*)&As[d][ty * 4];
      float4 b = *(const float4*)&Bs[d][tx * 4];
      acc[0][0] = fmaf(a.x, b.x, acc[0][0]); acc[0][1] = fmaf(a.x, b.y, acc[0][1]);
      acc[0][2] = fmaf(a.x, b.z, acc[0][2]); acc[0][3] = fmaf(a.x, b.w, acc[0][3]);
      acc[1][0] = fmaf(a.y, b.x, acc[1][0]); acc[1][1] = fmaf(a.y, b.y, acc[1][1]);
      acc[1][2] = fmaf(a.y, b.z, acc[1][2]); acc[1][3] = fmaf(a.y, b.w, acc[1][3]);
      acc[2][0] = fmaf(a.z, b.x, acc[2][0]); acc[2][1] = fmaf(a.z, b.y, acc[2][1]);
      acc[2][2] = fmaf(a.z, b.z, acc[2][2]); acc[2][3] = fmaf(a.z, b.w, acc[2][3]);
      acc[3][0] = fmaf(a.w, b.x, acc[3][0]); acc[3][1] = fmaf(a.w, b.y, acc[3][1]);
      acc[3][2] = fmaf(a.w, b.z, acc[3][2]); acc[3][3] = fmaf(a.w, b.w, acc[3][3]);
    }
    if (d0 == 352) {
#pragma unroll
      for (int i = 0; i < 4; ++i)
#pragma unroll
        for (int j = 0; j < 4; ++j) { p0[i][j] = acc[i][j]; acc[i][j] = 0.0f; }
    }
    if (d0 == 736) {
#pragma unroll
      for (int i = 0; i < 4; ++i)
#pragma unroll
        for (int j = 0; j < 4; ++j) { p1[i][j] = acc[i][j]; acc[i][j] = 0.0f; }
    }
  }
  {
#pragma clang fp contract(off)
#pragma unroll
    for (int i = 0; i < 4; ++i) {
      int t = t0 + ty * 4 + i;
      float sa = sf2[t];
      float o[4];
#pragma unroll
      for (int j = 0; j < 4; ++j) {
        float dot = (p0[i][j] + p1[i][j]) + acc[i][j];
        float two = 2.0f * dot;
        o[j] = (sa - two) + sc2[k0 + tx * 4 + j];
      }
      float4 ov; ov.x = o[0]; ov.y = o[1]; ov.z = o[2]; ov.w = o[3];
      *(float4*)&d2[(size_t)t * K_N + k0 + tx * 4] = ov;
    }
  }
}

// ---------------- dmin: exact per-row min of d2 (min is order-independent) ----------------
__global__ __launch_bounds__(256) void k_dmin(const float* __restrict__ d2,
                                              float* __restrict__ dminArr) {
  int wave = threadIdx.x >> 6;
  int lane = threadIdx.x & 63;
  int row = blockIdx.x * 4 + wave;
  const float4* p = (const float4*)(d2 + (size_t)row * K_N + lane * 16);
  float4 a = p[0], b = p[1], c = p[2], d = p[3];
  float m = fminf(fminf(fminf(a.x, a.y), fminf(a.z, a.w)),
                  fminf(fminf(b.x, b.y), fminf(b.z, b.w)));
  float n = fminf(fminf(fminf(c.x, c.y), fminf(c.z, c.w)),
                  fminf(fminf(d.x, d.y), fminf(d.z, d.w)));
  m = fminf(m, n);
  m = fminf(m, __shfl_xor(m, 1, 64));
  m = fminf(m, __shfl_xor(m, 2, 64));
  m = fminf(m, __shfl_xor(m, 4, 64));
  m = fminf(m, __shfl_xor(m, 8, 64));
  m = fminf(m, __shfl_xor(m, 16, 64));
  m = fminf(m, __shfl_xor(m, 32, 64));
  if (lane == 0) dminArr[row] = m;
}

// ---------------- DPP min chain (result valid in lane 63) ----------------
__device__ __forceinline__ float dpp_min_chain(float x) {
  int t;
  t = __builtin_amdgcn_update_dpp(__float_as_int(x), __float_as_int(x), 0x111, 0xF, 0xF, false);
  x = fminf(x, __int_as_float(t));
  t = __builtin_amdgcn_update_dpp(__float_as_int(x), __float_as_int(x), 0x112, 0xF, 0xF, false);
  x = fminf(x, __int_as_float(t));
  t = __builtin_amdgcn_update_dpp(__float_as_int(x), __float_as_int(x), 0x114, 0xF, 0xF, false);
  x = fminf(x, __int_as_float(t));
  t = __builtin_amdgcn_update_dpp(__float_as_int(x), __float_as_int(x), 0x118, 0xF, 0xF, false);
  x = fminf(x, __int_as_float(t));
  t = __builtin_amdgcn_update_dpp(__float_as_int(x), __float_as_int(x), 0x142, 0xF, 0xF, false); // row_bcast:15
  x = fminf(x, __int_as_float(t));
  t = __builtin_amdgcn_update_dpp(__float_as_int(x), __float_as_int(x), 0x143, 0xF, 0xF, false); // row_bcast:31
  x = fminf(x, __int_as_float(t));
  return x;
}
__device__ __forceinline__ float rdlane(float x, int l) {
  return __int_as_float(__builtin_amdgcn_readlane(__float_as_int(x), l));
}

// ---------------- pass1: 2-step-pipelined serial alpha chain (exact min algebra) ----------------
// f_t = min(pre_t, d_t + alpha_{t-1});  pre_{t+1} = d_{t+1} + (f_t - L)
// alpha_t = min(P_t, dmin_t + alpha_{t-1}),  P_t = min_k pre_t[k]  (reduced 1 step early)
// All identities exact in f32 (min exact; RN monotone) -> alpha bit-identical to reference.
__global__ __launch_bounds__(64, 1) void k_pass1(const float* __restrict__ d2,
                                                 const float* __restrict__ dminArr,
                                                 float* __restrict__ alphaOut) {
  const int lane = threadIdx.x;
  float pre[16];
  float4 rg[8][4];  // 8-row prefetch ring
#pragma unroll
  for (int j = 0; j < 16; ++j) pre[j] = BIGF;  // == d0 + (BIGF - L) exactly (d << ulp)
#pragma unroll
  for (int u = 0; u < 8; ++u) {
    const float4* rp = (const float4*)(d2 + (size_t)u * K_N + lane * 16);
#pragma unroll
    for (int q = 0; q < 4; ++q) rg[u][q] = rp[q];
  }
  float alpha = 0.0f;       // alpha_{-1}
  float vred = BIGF;        // pending reduce result: P_0 = 3e38 (uniform)
  float areg = 0.0f;
  float dmv_next = dminArr[lane];  // dmin block 0
  for (int b64 = 0; b64 < T_N; b64 += 64) {
    float dmv = dmv_next;
    int nb = b64 + 64; if (nb >= T_N) nb = 0;
    dmv_next = dminArr[nb + lane];  // prefetch next 64 dmins
    for (int b8 = 0; b8 < 64; b8 += 8) {
#pragma unroll
      for (int u = 0; u < 8; ++u) {
        int tau = b64 + b8 + u;
        // unpack current row d_tau and next row d_{tau+1} from ring
        float dc[16], dn[16];
        {
          float4 q0 = rg[u][0], q1 = rg[u][1], q2 = rg[u][2], q3 = rg[u][3];
          dc[0] = q0.x; dc[1] = q0.y; dc[2] = q0.z; dc[3] = q0.w;
          dc[4] = q1.x; dc[5] = q1.y; dc[6] = q1.z; dc[7] = q1.w;
          dc[8] = q2.x; dc[9] = q2.y; dc[10] = q2.z; dc[11] = q2.w;
          dc[12] = q3.x; dc[13] = q3.y; dc[14] = q3.z; dc[15] = q3.w;
        }
        // prefetch row tau+8 into slot u (row tau's last use is this iteration's A)
        int pr = tau + 8; if (pr > T_N - 1) pr = T_N - 1;
        const float4* rp = (const float4*)(d2 + (size_t)pr * K_N + lane * 16);
        float4 nf0 = rp[0], nf1 = rp[1], nf2 = rp[2], nf3 = rp[3];
        {
          int un = (u + 1) & 7;
          float4 q0 = rg[un][0], q1 = rg[un][1], q2 = rg[un][2], q3 = rg[un][3];
          dn[0] = q0.x; dn[1] = q0.y; dn[2] = q0.z; dn[3] = q0.w;
          dn[4] = q1.x; dn[5] = q1.y; dn[6] = q1.z; dn[7] = q1.w;
          dn[8] = q2.x; dn[9] = q2.y; dn[10] = q2.z; dn[11] = q2.w;
          dn[12] = q3.x; dn[13] = q3.y; dn[14] = q3.z; dn[15] = q3.w;
        }
        rg[u][0] = nf0; rg[u][1] = nf1; rg[u][2] = nf2; rg[u][3] = nf3;
        // A: f_tau = min(pre_tau, d_tau + alpha_{tau-1})   (exact == ref)
        float fv[16];
#pragma unroll
        for (int j = 0; j < 16; ++j) {
          float da = dc[j] + alpha;
          fv[j] = fminf(pre[j], da);
        }
        // B: pre_{tau+1} = d_{tau+1} + (f_tau - L)
#pragma unroll
        for (int j = 0; j < 16; ++j) {
          float ext = fv[j] - LMBDA;
          pre[j] = dn[j] + ext;
        }
        // C: reduce pre -> P_{tau+1} (min3 tree, depth 3, then DPP; consumed next iter)
        float m0 = fminf(fminf(pre[0], pre[1]), pre[2]);
        float m1 = fminf(fminf(pre[3], pre[4]), pre[5]);
        float m2 = fminf(fminf(pre[6], pre[7]), pre[8]);
        float m3 = fminf(fminf(pre[9], pre[10]), pre[11]);
        float m4 = fminf(fminf(pre[12], pre[13]), pre[14]);
        float n0 = fminf(fminf(m0, m1), m2);
        float n1 = fminf(fminf(m3, m4), pre[15]);
        float vred_new = dpp_min_chain(fminf(n0, n1));
        // D: alpha_tau = min(P_tau, dmin_tau + alpha_{tau-1})
        float P = rdlane(vred, 63);
        float sdm = rdlane(dmv, b8 + u);
        float danew = sdm + alpha;
        float anew = fminf(P, danew);
        alpha = anew;
        vred = vred_new;
        // record alpha_tau; burst store every 64 steps
        areg = ((tau & 63) == lane) ? anew : areg;
        if ((tau & 63) == 63) alphaOut[(tau & ~63) + lane] = areg;
      }
    }
  }
}

// ---------------- pass2: chunked warm-start replay per k (validated r1 == full-history r2) ----------------
#define CH 512
#define WARM 64
__global__ __launch_bounds__(256) void k_pass2(const float* __restrict__ d2,
                                               const float* __restrict__ AOUT,
                                               unsigned* __restrict__ pack) {
  int kb = blockIdx.x & 3;
  int tc = blockIdx.x >> 2;
  int k = kb * 256 + threadIdx.x;
  int ts = tc * CH;
  int start = ts - WARM; if (start < 0) start = 0;
  int end = ts + CH;
  __shared__ float lal[CH + WARM + 1];
  for (int i = threadIdx.x; i < end - start + 1; i += 256) {
    int idx = start - 1 + i;
    lal[i] = (idx < 0) ? 0.0f : AOUT[idx];
  }
  __syncthreads();
  float f = BIGF;
  unsigned s = 0;
#pragma unroll 4
  for (int tau = start; tau < end; ++tau) {
    float a_in = lal[tau - start];               // alpha before step tau
    float d = d2[(size_t)tau * K_N + k];
    float ext = f - LMBDA;
    if (a_in < ext) s = (unsigned)tau;           // take_new -> segment restarts at tau
    f = d + fminf(a_in, ext);                    // identical rounding to reference
    if (tau >= ts) {
      float a_out = lal[tau - start + 1];        // alpha after step tau
      if (f == a_out) atomicMin(&pack[tau], ((unsigned)k << 13) | s);  // first-min-k wins
    }
  }
}

// ---------------- backtrack: ballot run-skip serial chase + parallel fill (validated r1) ----------------
__global__ __launch_bounds__(256) void k_backtrack(const unsigned* __restrict__ pack,
                                                   unsigned* __restrict__ unitsWs,
                                                   float* __restrict__ outUnits) {
  __shared__ unsigned lp[T_N];
  __shared__ unsigned long long msk[T_N / 64];
  int tid = threadIdx.x;
  for (int i = tid * 4; i < T_N; i += 1024) {
    *(uint4*)&lp[i] = *(const uint4*)&pack[i];
  }
  __syncthreads();
  if (tid < 64) {
    int lane = tid;
    int cur = T_N;
    for (int B = T_N - 64; B >= 0; B -= 64) {
      unsigned long long marks = 0ull;
      if (cur > B) {
        unsigned pk = lp[B + lane];
        int bv = (int)(pk & 8191u);
        unsigned long long run = __ballot(bv == B + lane);  // beta==idx: descend-by-1
        while (cur > B) {
          int L = cur - 1 - B;
          unsigned long long below = (L == 63) ? ~0ull : ((1ull << (L + 1)) - 1ull);
          unsigned long long nz = (~run) & below;
          if (nz == 0ull) { marks |= below; cur = B; break; }
          int j = 63 - __builtin_clzll(nz);                  // first non-run lane <= L
          marks |= below & ~((1ull << j) - 1ull);            // visit [j, L]
          int nb = __builtin_amdgcn_readlane(bv, j);         // jump
          cur = nb;
          if (cur > B + j) cur = B + j;                      // defensive: force progress
        }
      }
      if (lane == 0) msk[B >> 6] = marks;
    }
  }
  __syncthreads();
  // units[p] = gamma at the smallest chain mark >= p
  for (int p = tid; p < T_N; p += 256) {
    int w = p >> 6;
    unsigned long long m = msk[w] & (~0ull << (p & 63));
    while (m == 0ull) { ++w; m = msk[w]; }
    int idx = (w << 6) + (int)__builtin_ctzll(m);
    unsigned g = (lp[idx] >> 13) & 1023u;
    unitsWs[p] = g;
    outUnits[p] = (float)g;
  }
}

// ---------------- gather: quantized[t] = codebook[units[t]] ----------------
__global__ __launch_bounds__(256) void k_gather(const float* __restrict__ C,
                                                const unsigned* __restrict__ unitsWs,
                                                float* __restrict__ out) {
  int t = blockIdx.x;
  unsigned u = unitsWs[t] & 1023u;
  const float4* src = (const float4*)(C + (size_t)u * D_N);
  float4* dst = (float4*)(out + (size_t)t * D_N);
  dst[threadIdx.x] = src[threadIdx.x];
}

extern "C" void kernel_launch(void* const* d_in, const int* in_sizes, int n_in,
                              void* d_out, int out_size, void* d_ws, size_t ws_size,
                              hipStream_t stream) {
  const float* F = (const float*)d_in[0];
  const float* C = (const float*)d_in[1];
  float* out = (float*)d_out;
  float* d2 = out;                                  // reuse quantized region as d2 scratch
  float* outUnits = out + (size_t)T_N * D_N;
  char* ws = (char*)d_ws;
  float* alphaOut = (float*)(ws);                    // 32 KB
  unsigned* pack = (unsigned*)(ws + (32 << 10));     // 32 KB
  unsigned* unitsWs = (unsigned*)(ws + (64 << 10));  // 32 KB
  float* sf2 = (float*)(ws + (96 << 10));            // 32 KB
  float* sc2 = (float*)(ws + (128 << 10));           // 4 KB
  float* dminArr = (float*)(ws + (160 << 10));       // 32 KB

  k_norms<<<(T_N + K_N) / 4, 256, 0, stream>>>(F, C, sf2, sc2);
  hipMemsetAsync(pack, 0xFF, T_N * sizeof(unsigned), stream);
  k_gemm<<<(T_N / 64) * (K_N / 64), 256, 0, stream>>>(F, C, sf2, sc2, d2);
  k_dmin<<<T_N / 4, 256, 0, stream>>>(d2, dminArr);
  k_pass1<<<1, 64, 0, stream>>>(d2, dminArr, alphaOut);
  k_pass2<<<(T_N / CH) * 4, 256, 0, stream>>>(d2, alphaOut, pack);
  k_backtrack<<<1, 256, 0, stream>>>(pack, unitsWs, outUnits);
  k_gather<<<T_N, 256, 0, stream>>>(C, unitsWs, out);
}

// Round 7
// 2171.454 us; speedup vs baseline: 1.0820x; 1.0820x over previous
//
#include <hip/hip_runtime.h>
#include <hip/hip_bf16.h>
#include <stdint.h>

#define T_N 8192
#define K_N 1024
#define D_N 1024
#define LMBDA 5.0f
#define BIGF 3.0e38f

// ---------------- norms: numpy-pairwise-exact sum of squares per row ----------------
__global__ __launch_bounds__(256) void k_norms(const float* __restrict__ F,
                                               const float* __restrict__ C,
                                               float* __restrict__ sf2,
                                               float* __restrict__ sc2) {
#pragma clang fp contract(off)
  int wave = threadIdx.x >> 6;
  int lane = threadIdx.x & 63;
  int row = blockIdx.x * 4 + wave;
  const float* src;
  float* dst;
  if (row < T_N) { src = F + (size_t)row * D_N; dst = sf2 + row; }
  else           { src = C + (size_t)(row - T_N) * D_N; dst = sc2 + (row - T_N); }
  int leaf = lane >> 3, j = lane & 7;
  const float* p = src + leaf * 128 + j;
  float x = p[0];
  float r = x * x;
#pragma unroll
  for (int i = 1; i < 16; ++i) {
    float y = p[8 * i];
    r = r + y * y;
  }
  r = r + __shfl_xor(r, 1, 64);
  r = r + __shfl_xor(r, 2, 64);
  r = r + __shfl_xor(r, 4, 64);
  r = r + __shfl_xor(r, 8, 64);
  r = r + __shfl_xor(r, 16, 64);
  r = r + __shfl_xor(r, 32, 64);
  if (lane == 0) *dst = r;
}

// ---------------- d2 GEMM: OpenBLAS-faithful f32 (numerics frozen — do not reorder) ----------------
__global__ __launch_bounds__(256) void k_gemm(const float* __restrict__ F,
                                              const float* __restrict__ C,
                                              const float* __restrict__ sf2,
                                              const float* __restrict__ sc2,
                                              float* __restrict__ d2) {
  __shared__ float As[32][68];
  __shared__ float Bs[32][68];
  int t0 = (int)(blockIdx.x >> 4) * 64;
  int k0 = (int)(blockIdx.x & 15) * 64;
  int tid = threadIdx.x;
  int tx = tid & 15, ty = tid >> 4;
  float acc[4][4], p0[4][4], p1[4][4];
#pragma unroll
  for (int i = 0; i < 4; ++i)
#pragma unroll
    for (int j = 0; j < 4; ++j) { acc[i][j] = 0.0f; p0[i][j] = 0.0f; p1[i][j] = 0.0f; }
  int r = tid & 63;
  int cbase = (tid >> 6) * 2;
  for (int d0 = 0; d0 < D_N; d0 += 32) {
    __syncthreads();
#pragma unroll
    for (int p = 0; p < 2; ++p) {
      int c4 = cbase + p;
      float4 va = *(const float4*)&F[(size_t)(t0 + r) * D_N + d0 + c4 * 4];
      As[c4 * 4 + 0][r] = va.x; As[c4 * 4 + 1][r] = va.y;
      As[c4 * 4 + 2][r] = va.z; As[c4 * 4 + 3][r] = va.w;
      float4 vb = *(const float4*)&C[(size_t)(k0 + r) * D_N + d0 + c4 * 4];
      Bs[c4 * 4 + 0][r] = vb.x; Bs[c4 * 4 + 1][r] = vb.y;
      Bs[c4 * 4 + 2][r] = vb.z; Bs[c4 * 4 + 3][r] = vb.w;
    }
    __syncthreads();
#pragma unroll
    for (int d = 0; d < 32; ++d) {
      float4 a = *(const float4*)&As[d][ty * 4];
      float4 b = *(const float4*)&Bs[d][tx * 4];
      acc[0][0] = fmaf(a.x, b.x, acc[0][0]); acc[0][1] = fmaf(a.x, b.y, acc[0][1]);
      acc[0][2] = fmaf(a.x, b.z, acc[0][2]); acc[0][3] = fmaf(a.x, b.w, acc[0][3]);
      acc[1][0] = fmaf(a.y, b.x, acc[1][0]); acc[1][1] = fmaf(a.y, b.y, acc[1][1]);
      acc[1][2] = fmaf(a.y, b.z, acc[1][2]); acc[1][3] = fmaf(a.y, b.w, acc[1][3]);
      acc[2][0] = fmaf(a.z, b.x, acc[2][0]); acc[2][1] = fmaf(a.z, b.y, acc[2][1]);
      acc[2][2] = fmaf(a.z, b.z, acc[2][2]); acc[2][3] = fmaf(a.z, b.w, acc[2][3]);
      acc[3][0] = fmaf(a.w, b.x, acc[3][0]); acc[3][1] = fmaf(a.w, b.y, acc[3][1]);
      acc[3][2] = fmaf(a.w, b.z, acc[3][2]); acc[3][3] = fmaf(a.w, b.w, acc[3][3]);
    }
    if (d0 == 352) {
#pragma unroll
      for (int i = 0; i < 4; ++i)
#pragma unroll
        for (int j = 0; j < 4; ++j) { p0[i][j] = acc[i][j]; acc[i][j] = 0.0f; }
    }
    if (d0 == 736) {
#pragma unroll
      for (int i = 0; i < 4; ++i)
#pragma unroll
        for (int j = 0; j < 4; ++j) { p1[i][j] = acc[i][j]; acc[i][j] = 0.0f; }
    }
  }
  {
#pragma clang fp contract(off)
#pragma unroll
    for (int i = 0; i < 4; ++i) {
      int t = t0 + ty * 4 + i;
      float sa = sf2[t];
      float o[4];
#pragma unroll
      for (int j = 0; j < 4; ++j) {
        float dot = (p0[i][j] + p1[i][j]) + acc[i][j];
        float two = 2.0f * dot;
        o[j] = (sa - two) + sc2[k0 + tx * 4 + j];
      }
      float4 ov; ov.x = o[0]; ov.y = o[1]; ov.z = o[2]; ov.w = o[3];
      *(float4*)&d2[(size_t)t * K_N + k0 + tx * 4] = ov;
    }
  }
}

// ---------------- dmin: exact per-row min of d2 (min is order-independent) ----------------
__global__ __launch_bounds__(256) void k_dmin(const float* __restrict__ d2,
                                              float* __restrict__ dminArr) {
  int wave = threadIdx.x >> 6;
  int lane = threadIdx.x & 63;
  int row = blockIdx.x * 4 + wave;
  const float4* p = (const float4*)(d2 + (size_t)row * K_N + lane * 16);
  float4 a = p[0], b = p[1], c = p[2], d = p[3];
  float m = fminf(fminf(fminf(a.x, a.y), fminf(a.z, a.w)),
                  fminf(fminf(b.x, b.y), fminf(b.z, b.w)));
  float n = fminf(fminf(fminf(c.x, c.y), fminf(c.z, c.w)),
                  fminf(fminf(d.x, d.y), fminf(d.z, d.w)));
  m = fminf(m, n);
  m = fminf(m, __shfl_xor(m, 1, 64));
  m = fminf(m, __shfl_xor(m, 2, 64));
  m = fminf(m, __shfl_xor(m, 4, 64));
  m = fminf(m, __shfl_xor(m, 8, 64));
  m = fminf(m, __shfl_xor(m, 16, 64));
  m = fminf(m, __shfl_xor(m, 32, 64));
  if (lane == 0) dminArr[row] = m;
}

// ---------------- DPP min chain (result valid in lane 63) ----------------
__device__ __forceinline__ float dpp_min_chain(float x) {
  int t;
  t = __builtin_amdgcn_update_dpp(__float_as_int(x), __float_as_int(x), 0x111, 0xF, 0xF, false);
  x = fminf(x, __int_as_float(t));
  t = __builtin_amdgcn_update_dpp(__float_as_int(x), __float_as_int(x), 0x112, 0xF, 0xF, false);
  x = fminf(x, __int_as_float(t));
  t = __builtin_amdgcn_update_dpp(__float_as_int(x), __float_as_int(x), 0x114, 0xF, 0xF, false);
  x = fminf(x, __int_as_float(t));
  t = __builtin_amdgcn_update_dpp(__float_as_int(x), __float_as_int(x), 0x118, 0xF, 0xF, false);
  x = fminf(x, __int_as_float(t));
  t = __builtin_amdgcn_update_dpp(__float_as_int(x), __float_as_int(x), 0x142, 0xF, 0xF, false); // row_bcast:15
  x = fminf(x, __int_as_float(t));
  t = __builtin_amdgcn_update_dpp(__float_as_int(x), __float_as_int(x), 0x143, 0xF, 0xF, false); // row_bcast:31
  x = fminf(x, __int_as_float(t));
  return x;
}
__device__ __forceinline__ float rdlane(float x, int l) {
  return __int_as_float(__builtin_amdgcn_readlane(__float_as_int(x), l));
}

// ---------------- pass1: 4-wave pipelined serial alpha chain ----------------
// r6-validated exact algebra, work split over 4 waves (256 k each, 4 k/lane):
//   fv_t = min(pre_t, d_t + a_{t-1})             (bit == ref f_t)
//   pre_{t+1} = d_{t+1} + (fv_t - L)
//   P_{t+1} = min_k pre_{t+1}  (per-wave DPP partial -> LDS, combined next step)
//   a_t = min(P_t, dmin_t + a_{t-1})             (bit == ref alpha_t)
// One raw s_barrier per step; slot parity is compile-time within the unroll-8.
__global__ __launch_bounds__(256, 1) void k_pass1(const float* __restrict__ d2,
                                                  const float* __restrict__ dminArr,
                                                  float* __restrict__ alphaOut) {
  __shared__ float ldsP[2][4];
  const int tid = threadIdx.x;
  const int lane = tid & 63;
  const int wid = tid >> 6;
  const float* base = d2 + (size_t)(wid * 256 + lane * 4);
  float4 rg[8];     // 8-row prefetch ring, 1 float4/lane/row
  float pre[4];
#pragma unroll
  for (int u = 0; u < 8; ++u) rg[u] = *(const float4*)(base + (size_t)u * K_N);
#pragma unroll
  for (int j = 0; j < 4; ++j) pre[j] = BIGF;   // pre_0 = d_0 + (BIG-L) == BIG exactly
  if (tid < 8) ((float*)ldsP)[tid] = BIGF;     // P_0 partials
  asm volatile("s_waitcnt lgkmcnt(0)" ::: "memory");
  __builtin_amdgcn_s_barrier();
  asm volatile("" ::: "memory");
  float alpha = 0.0f;   // alpha_{-1}
  float areg = 0.0f;
  float dmv_next = dminArr[lane];
  for (int b64 = 0; b64 < T_N; b64 += 64) {
    float dmv = dmv_next;
    int nb = b64 + 64; if (nb >= T_N) nb = 0;
    dmv_next = dminArr[nb + lane];
    for (int b8 = 0; b8 < 64; b8 += 8) {
#pragma unroll
      for (int u = 0; u < 8; ++u) {
        int tau = b64 + b8 + u;
        // 1. read P_tau partials (written at iter tau-1 into slot[(tau-1)&1] = [(u+1)&1])
        float4 q = *(const float4*)&ldsP[(u + 1) & 1][0];
        // 2. A: fv = min(pre, d_tau + alpha_{tau-1})
        float4 dc = rg[u];
        float fv0 = fminf(pre[0], dc.x + alpha);
        float fv1 = fminf(pre[1], dc.y + alpha);
        float fv2 = fminf(pre[2], dc.z + alpha);
        float fv3 = fminf(pre[3], dc.w + alpha);
        // 3. prefetch row tau+8 into slot u (after dc's last read)
        int pr = tau + 8; if (pr > T_N - 1) pr = T_N - 1;
        rg[u] = *(const float4*)(base + (size_t)pr * K_N);
        // 4. B: pre_{tau+1} = d_{tau+1} + (fv - L); d_{tau+1} = slot (u+1)&7
        float4 dn = rg[(u + 1) & 7];
        pre[0] = dn.x + (fv0 - LMBDA);
        pre[1] = dn.y + (fv1 - LMBDA);
        pre[2] = dn.z + (fv2 - LMBDA);
        pre[3] = dn.w + (fv3 - LMBDA);
        // 5. C: per-wave partial P_{tau+1} (min3 + min + DPP; valid lane 63)
        float c = fminf(fminf(fminf(pre[0], pre[1]), pre[2]), pre[3]);
        c = dpp_min_chain(c);
        // 6. F: alpha_tau = min(P_tau, dmin_tau + alpha_{tau-1})
        float sdm = rdlane(dmv, b8 + u);
        float da = sdm + alpha;
        float Pt = fminf(fminf(fminf(q.x, q.y), q.z), q.w);
        alpha = fminf(Pt, da);
        // 7. D: publish partial for P_{tau+1} into slot[tau&1] = [u&1]
        if (lane == 63) ldsP[u & 1][wid] = c;
        // 8. record alpha (wave 0 only), burst store every 64 steps
        if (wid == 0) {
          areg = ((tau & 63) == lane) ? alpha : areg;
          if ((tau & 63) == 63) alphaOut[(tau & ~63) + lane] = areg;
        }
        asm volatile("s_waitcnt lgkmcnt(0)" ::: "memory");
        __builtin_amdgcn_s_barrier();
        asm volatile("" ::: "memory");
      }
    }
  }
}

// ---------------- pass2: chunked warm-start replay per k (validated r1 == full-history r2) ----------------
#define CH 512
#define WARM 64
__global__ __launch_bounds__(256) void k_pass2(const float* __restrict__ d2,
                                               const float* __restrict__ AOUT,
                                               unsigned* __restrict__ pack) {
  int kb = blockIdx.x & 3;
  int tc = blockIdx.x >> 2;
  int k = kb * 256 + threadIdx.x;
  int ts = tc * CH;
  int start = ts - WARM; if (start < 0) start = 0;
  int end = ts + CH;
  __shared__ float lal[CH + WARM + 1];
  for (int i = threadIdx.x; i < end - start + 1; i += 256) {
    int idx = start - 1 + i;
    lal[i] = (idx < 0) ? 0.0f : AOUT[idx];
  }
  __syncthreads();
  float f = BIGF;
  unsigned s = 0;
#pragma unroll 4
  for (int tau = start; tau < end; ++tau) {
    float a_in = lal[tau - start];               // alpha before step tau
    float d = d2[(size_t)tau * K_N + k];
    float ext = f - LMBDA;
    if (a_in < ext) s = (unsigned)tau;           // take_new -> segment restarts at tau
    f = d + fminf(a_in, ext);                    // identical rounding to reference
    if (tau >= ts) {
      float a_out = lal[tau - start + 1];        // alpha after step tau
      if (f == a_out) atomicMin(&pack[tau], ((unsigned)k << 13) | s);  // first-min-k wins
    }
  }
}

// ---------------- backtrack: ballot run-skip serial chase + parallel fill (validated r1) ----------------
__global__ __launch_bounds__(256) void k_backtrack(const unsigned* __restrict__ pack,
                                                   unsigned* __restrict__ unitsWs,
                                                   float* __restrict__ outUnits) {
  __shared__ unsigned lp[T_N];
  __shared__ unsigned long long msk[T_N / 64];
  int tid = threadIdx.x;
  for (int i = tid * 4; i < T_N; i += 1024) {
    *(uint4*)&lp[i] = *(const uint4*)&pack[i];
  }
  __syncthreads();
  if (tid < 64) {
    int lane = tid;
    int cur = T_N;
    for (int B = T_N - 64; B >= 0; B -= 64) {
      unsigned long long marks = 0ull;
      if (cur > B) {
        unsigned pk = lp[B + lane];
        int bv = (int)(pk & 8191u);
        unsigned long long run = __ballot(bv == B + lane);  // beta==idx: descend-by-1
        while (cur > B) {
          int L = cur - 1 - B;
          unsigned long long below = (L == 63) ? ~0ull : ((1ull << (L + 1)) - 1ull);
          unsigned long long nz = (~run) & below;
          if (nz == 0ull) { marks |= below; cur = B; break; }
          int j = 63 - __builtin_clzll(nz);                  // first non-run lane <= L
          marks |= below & ~((1ull << j) - 1ull);            // visit [j, L]
          int nb = __builtin_amdgcn_readlane(bv, j);         // jump
          cur = nb;
          if (cur > B + j) cur = B + j;                      // defensive: force progress
        }
      }
      if (lane == 0) msk[B >> 6] = marks;
    }
  }
  __syncthreads();
  // units[p] = gamma at the smallest chain mark >= p
  for (int p = tid; p < T_N; p += 256) {
    int w = p >> 6;
    unsigned long long m = msk[w] & (~0ull << (p & 63));
    while (m == 0ull) { ++w; m = msk[w]; }
    int idx = (w << 6) + (int)__builtin_ctzll(m);
    unsigned g = (lp[idx] >> 13) & 1023u;
    unitsWs[p] = g;
    outUnits[p] = (float)g;
  }
}

// ---------------- gather: quantized[t] = codebook[units[t]] ----------------
__global__ __launch_bounds__(256) void k_gather(const float* __restrict__ C,
                                                const unsigned* __restrict__ unitsWs,
                                                float* __restrict__ out) {
  int t = blockIdx.x;
  unsigned u = unitsWs[t] & 1023u;
  const float4* src = (const float4*)(C + (size_t)u * D_N);
  float4* dst = (float4*)(out + (size_t)t * D_N);
  dst[threadIdx.x] = src[threadIdx.x];
}

extern "C" void kernel_launch(void* const* d_in, const int* in_sizes, int n_in,
                              void* d_out, int out_size, void* d_ws, size_t ws_size,
                              hipStream_t stream) {
  const float* F = (const float*)d_in[0];
  const float* C = (const float*)d_in[1];
  float* out = (float*)d_out;
  float* d2 = out;                                  // reuse quantized region as d2 scratch
  float* outUnits = out + (size_t)T_N * D_N;
  char* ws = (char*)d_ws;
  float* alphaOut = (float*)(ws);                    // 32 KB
  unsigned* pack = (unsigned*)(ws + (32 << 10));     // 32 KB
  unsigned* unitsWs = (unsigned*)(ws + (64 << 10));  // 32 KB
  float* sf2 = (float*)(ws + (96 << 10));            // 32 KB
  float* sc2 = (float*)(ws + (128 << 10));           // 4 KB
  float* dminArr = (float*)(ws + (160 << 10));       // 32 KB

  k_norms<<<(T_N + K_N) / 4, 256, 0, stream>>>(F, C, sf2, sc2);
  hipMemsetAsync(pack, 0xFF, T_N * sizeof(unsigned), stream);
  k_gemm<<<(T_N / 64) * (K_N / 64), 256, 0, stream>>>(F, C, sf2, sc2, d2);
  k_dmin<<<T_N / 4, 256, 0, stream>>>(d2, dminArr);
  k_pass1<<<1, 256, 0, stream>>>(d2, dminArr, alphaOut);
  k_pass2<<<(T_N / CH) * 4, 256, 0, stream>>>(d2, alphaOut, pack);
  k_backtrack<<<1, 256, 0, stream>>>(pack, unitsWs, outUnits);
  k_gather<<<T_N, 256, 0, stream>>>(C, unitsWs, out);
}